// Round 10
// baseline (271.535 us; speedup 1.0000x reference)
//
#include <hip/hip_runtime.h>

// R-GCN layer: out[v] = sum_{e: dst[e]=v} norm[e] * (h[src[e]] @ W[rel[e]])
//
// v10: rel-group pipelining for L3 residency. T (205MB) straddled the 256MB
// Infinity Cache, forcing a full HBM round-trip (k_pre write-roofline 68.8us).
// Split rels into G=2 groups: pre(0)->out(0)->pre(1)->out(1); each T_g =
// 102.4MB fits L3, so out(g)'s random gathers hit L3 and pre(g)'s stores land
// at L3-accept rate with HBM drain overlapping the latency-bound out(g).
// Edges are group-partitioned: 782 buckets (g*391 + dst>>7), offs[2][50001].
// Occupancy fixes: scatter2 EPB 8192->4096 (LDS 85->50KB, 3 blocks/CU);
// sort cap 3072 for halved buckets (25.6KB, 6 blocks/CU).
//   k_hist2    coarse histogram (782 g-buckets)
//   k_scanc    scan of 782 bucket counts
//   k_scatter2 per-block LDS counting sort of 4096 edges -> burst writes
//   k_sort     per-bucket exact sort by dst + offs[g][node]
//   k_wconv    pack W -> per-lane bf16 MFMA fragments
//   k_pre      T[rl][n][:] = bf16(h[n] @ W[g*16+rl]), h staged per chunk
//   k_out      one wave per dst node, masked 8-wide gather-FMA, RMW for g=1

#define N_NODES 50000
#define N_EDGES 1600000
#define D 64
#define N_REL 32
#define NGRP 2
#define RPG 16                   // rels per group

#define BSHIFT 7                 // 128 nodes per coarse bucket
#define NPB 128
#define NB 391                   // buckets per group
#define NB2 782                  // total buckets (g*391 + dst>>7)
#define EPB 4096                 // edges per scatter/hist block
#define SC_BLOCKS 391            // ceil(1.6M/4096)
#define SORT_CAP 3072            // bucket capacity (mean 2046, sd 45 -> +23sd)

#define PRE_CHUNK 64
#define PRE_BLOCKS 782           // ceil(50000/64)
#define RELS_PER_BLOCK 8

typedef __attribute__((ext_vector_type(8))) __bf16 bf16x8;
typedef __attribute__((ext_vector_type(4))) __bf16 bf16x4;
typedef __attribute__((ext_vector_type(4))) float f32x4;

// ws layout (bytes):
//   [0x0000, 0x1000)      gcnt[NB2] ints
//   [0x1000, 0x2000)      base[NB2+1] ints
//   [0x2000, 0x3000)      cursor[NB2] ints
//   [0x3000, 0x65000)     offs[2][50001] ints (400 KB)
//   [0x100000, 0xD40000)  payload int2[1.6M] (12.8 MB)
//   [0xD40000, 0xD80000)  Wfrag bf16 [32][2][4][64][8]  (256 KB)
//   [0xE00000, ...)       T bf16 [RPG][N_NODES][64]  (102.4 MB)

__global__ __launch_bounds__(512) void k_zeroc(int* __restrict__ gcnt) {
    int t = threadIdx.x;
    if (t < NB2) gcnt[t] = 0;
    if (t + 512 < NB2) gcnt[t + 512] = 0;
}

__global__ __launch_bounds__(256) void k_hist2(const int* __restrict__ dst,
                                               const int* __restrict__ rel,
                                               int* __restrict__ gcnt) {
    __shared__ int lc[NB2];
    for (int b = threadIdx.x; b < NB2; b += 256) lc[b] = 0;
    __syncthreads();
    const int e0 = blockIdx.x * EPB;
    #pragma unroll
    for (int j = 0; j < 16; ++j) {
        int e = e0 + j * 256 + threadIdx.x;
        if (e < N_EDGES) {
            int b = ((rel[e] >> 4) ? NB : 0) + (dst[e] >> BSHIFT);
            atomicAdd(&lc[b], 1);
        }
    }
    __syncthreads();
    for (int b = threadIdx.x; b < NB2; b += 256)
        if (lc[b]) atomicAdd(&gcnt[b], lc[b]);
}

// Exclusive scan of gcnt[0..NB2) -> base[0..NB2], base[NB2]=total; cursor=base.
// 256 threads, 4 contiguous elems per thread.
__global__ __launch_bounds__(256) void k_scanc(const int* __restrict__ gcnt,
                                               int* __restrict__ base,
                                               int* __restrict__ cur) {
    __shared__ int wt[4];
    const int t = threadIdx.x;
    const int lane = t & 63;
    const int w = t >> 6;
    const int b0 = t * 4;
    int c[4], lp[4];
    int ls = 0;
    #pragma unroll
    for (int j = 0; j < 4; ++j) {
        int idx = b0 + j;
        c[j] = (idx < NB2) ? gcnt[idx] : 0;
        lp[j] = ls;
        ls += c[j];
    }
    int x = ls;
    #pragma unroll
    for (int d = 1; d < 64; d <<= 1) {
        int n = __shfl_up(x, d, 64);
        if (lane >= d) x += n;
    }
    if (lane == 63) wt[w] = x;
    __syncthreads();
    if (t == 0) {
        int run = 0;
        #pragma unroll
        for (int i = 0; i < 4; ++i) { int tmp = wt[i]; wt[i] = run; run += tmp; }
    }
    __syncthreads();
    int tbase = x - ls + wt[w];
    #pragma unroll
    for (int j = 0; j < 4; ++j) {
        int idx = b0 + j;
        if (idx < NB2) { base[idx] = tbase + lp[j]; cur[idx] = tbase + lp[j]; }
        if (idx == NB2 - 1) base[NB2] = tbase + lp[j] + c[j];
    }
}

// Per-block LDS counting sort of 4096 edges into NB2 g-buckets, then
// burst-write contiguous per-bucket runs to globally reserved ranges.
// payload: x = (dstLocal<<21) | (rel*N_NODES + src), y = bits(norm)
__global__ __launch_bounds__(256) void k_scatter2(
        const int* __restrict__ src, const int* __restrict__ dst,
        const int* __restrict__ rel, const float* __restrict__ norm,
        int* __restrict__ cur, int2* __restrict__ pay) {
    __shared__ int cnt[NB2];
    __shared__ int bl[NB2 + 1];
    __shared__ int gb[NB2];
    __shared__ unsigned short bid[EPB];
    __shared__ int2 stage[EPB];
    __shared__ int wt[4];

    const int t = threadIdx.x;
    const int lane = t & 63;
    const int w = t >> 6;
    const int e0 = blockIdx.x * EPB;

    for (int b = t; b < NB2; b += 256) cnt[b] = 0;
    __syncthreads();

    // pass 1: count
    #pragma unroll
    for (int j = 0; j < 16; ++j) {
        int e = e0 + j * 256 + t;
        if (e < N_EDGES) {
            int b = ((rel[e] >> 4) ? NB : 0) + (dst[e] >> BSHIFT);
            atomicAdd(&cnt[b], 1);
        }
    }
    __syncthreads();

    // exclusive scan of cnt[0..NB2): 4 contiguous elems per thread
    {
        const int b0 = t * 4;
        int c[4], lp[4];
        int ls = 0;
        #pragma unroll
        for (int j = 0; j < 4; ++j) {
            int idx = b0 + j;
            c[j] = (idx < NB2) ? cnt[idx] : 0;
            lp[j] = ls;
            ls += c[j];
        }
        int x = ls;
        #pragma unroll
        for (int d = 1; d < 64; d <<= 1) {
            int n = __shfl_up(x, d, 64);
            if (lane >= d) x += n;
        }
        if (lane == 63) wt[w] = x;
        __syncthreads();
        if (t == 0) {
            int run = 0;
            #pragma unroll
            for (int i = 0; i < 4; ++i) { int tmp = wt[i]; wt[i] = run; run += tmp; }
        }
        __syncthreads();
        int tbase = x - ls + wt[w];
        #pragma unroll
        for (int j = 0; j < 4; ++j) {
            int idx = b0 + j;
            if (idx < NB2) bl[idx] = tbase + lp[j];
        }
        if (t == 0) {
            int tot = (e0 + EPB <= N_EDGES) ? EPB : (N_EDGES > e0 ? N_EDGES - e0 : 0);
            bl[NB2] = tot;
        }
    }
    __syncthreads();

    // reserve global ranges (one atomic per non-empty bucket per block)
    for (int b = t; b < NB2; b += 256) {
        int c = bl[b + 1] - bl[b];
        gb[b] = c ? atomicAdd(&cur[b], c) : 0;
    }
    for (int b = t; b < NB2; b += 256) cnt[b] = 0;
    __syncthreads();

    // pass 2: stage into LDS in bucket-grouped order
    #pragma unroll
    for (int j = 0; j < 16; ++j) {
        int e = e0 + j * 256 + t;
        if (e < N_EDGES) {
            int dv = dst[e];
            int rv = rel[e];
            int b = ((rv >> 4) ? NB : 0) + (dv >> BSHIFT);
            int r = atomicAdd(&cnt[b], 1);
            int pos = bl[b] + r;
            stage[pos] = make_int2(((dv & (NPB - 1)) << 21) | (rv * N_NODES + src[e]),
                                   __float_as_int(norm[e]));
            bid[pos] = (unsigned short)b;
        }
    }
    __syncthreads();

    // pass 3: burst write to global reserved ranges (coalesced runs)
    const int total = bl[NB2];
    for (int p = t; p < total; p += 256) {
        int b = bid[p];
        pay[gb[b] + (p - bl[b])] = stage[p];
    }
}

// One block per g-bucket: stage the bucket's edges in LDS, counting-sort by
// exact local dst, write back IN PLACE sorted, emit per-(g,node) offsets.
__global__ __launch_bounds__(512) void k_sort(
        const int* __restrict__ base, int2* __restrict__ pay,
        int* __restrict__ offs) {
    __shared__ int2 stage[SORT_CAP];   // 24 KB
    __shared__ int cnt[NPB];
    __shared__ int curl[NPB];
    __shared__ int wsum[2];

    const int t = threadIdx.x;
    const int lane = t & 63;
    const int b = blockIdx.x;
    const int g = (b >= NB) ? 1 : 0;
    const int lb = b - g * NB;
    const int og = g * (N_NODES + 1);
    const int s = base[b];
    const int e = base[b + 1];
    const int n = min(e - s, SORT_CAP);   // clamp: overflow degrades, never faults

    if (t < NPB) cnt[t] = 0;
    __syncthreads();

    // stage + count
    for (int j = t; j < n; j += 512) {
        int2 p = pay[s + j];
        stage[j] = p;
        atomicAdd(&cnt[p.x >> 21], 1);
    }
    __syncthreads();

    // exclusive scan of cnt[0..128) with 2 waves
    int vcnt = 0, x = 0;
    if (t < NPB) {
        vcnt = cnt[t];
        x = vcnt;
        #pragma unroll
        for (int d = 1; d < 64; d <<= 1) {
            int nn = __shfl_up(x, d, 64);
            if (lane >= d) x += nn;
        }
        if (lane == 63) wsum[t >> 6] = x;
    }
    __syncthreads();
    if (t < NPB) {
        int excl = x - vcnt + ((t >= 64) ? wsum[0] : 0);
        curl[t] = excl;
        int node = lb * NPB + t;
        if (node < N_NODES) offs[og + node] = s + excl;
    }
    if (lb == NB - 1 && t == 0) offs[og + N_NODES] = e;
    __syncthreads();

    // scatter back in place, sorted by local dst
    for (int j = t; j < n; j += 512) {
        int2 p = stage[j];
        int pos = atomicAdd(&curl[p.x >> 21], 1);
        pay[s + pos] = p;
    }
}

// Pack W into per-lane MFMA A-fragment order:
// Wfrag[r][kt][ot][lane][j] = bf16( W[r][kt*32 + (lane>>4)*8 + j][ot*16 + (lane&15)] )
__global__ __launch_bounds__(256) void k_wconv(const float* __restrict__ W,
                                               __bf16* __restrict__ Wfrag) {
    const int r = blockIdx.x;
    const int lane = threadIdx.x & 63;
    const int jj = (threadIdx.x >> 6) * 2;   // 2 elems per thread per frag
    const int q = lane >> 4;
    const int m = lane & 15;
    const float* Wr = W + (size_t)r * D * D;
    #pragma unroll
    for (int kt = 0; kt < 2; ++kt) {
        #pragma unroll
        for (int ot = 0; ot < 4; ++ot) {
            size_t dbase = ((((size_t)r * 2 + kt) * 4 + ot) * 64 + lane) * 8 + jj;
            Wfrag[dbase]     = (__bf16)Wr[(kt * 32 + q * 8 + jj) * D + ot * 16 + m];
            Wfrag[dbase + 1] = (__bf16)Wr[(kt * 32 + q * 8 + jj + 1) * D + ot * 16 + m];
        }
    }
}

// T[rl][n][:] = h[n] @ W[r0+rl], bf16, rl in [0,RPG).  One block per
// (64-node chunk, 8-rel subgroup); h staged once in LDS (bf16, XOR-swizzled);
// waves loop over rels reading packed Wfrag. Plain stores (L2 write-combines).
__global__ __launch_bounds__(256) void k_pre(
        const float* __restrict__ h, const __bf16* __restrict__ Wfrag,
        __bf16* __restrict__ T, int r0) {
    __shared__ unsigned short hl[PRE_CHUNK * D];   // 8 KB
    const int t = threadIdx.x;
    const int lane = t & 63;
    const int w = t >> 6;
    const int m = lane & 15;
    const int q = lane >> 4;
    const int chunk0 = blockIdx.x * PRE_CHUNK;
    const int rlb = blockIdx.y * RELS_PER_BLOCK;

    // stage h[chunk0 .. chunk0+64) as bf16, swizzled
    #pragma unroll
    for (int it = 0; it < 4; ++it) {
        int F = it * 256 + t;                  // float4 index over 64x64 floats
        int row = F >> 4;
        int gnode = min(chunk0 + row, N_NODES - 1);
        float4 v = ((const float4*)(h + (size_t)gnode * D))[F & 15];
        int c = (F & 15) >> 1;
        int off4 = (F & 1) * 4;
        bf16x4 o;
        o[0] = (__bf16)v.x; o[1] = (__bf16)v.y; o[2] = (__bf16)v.z; o[3] = (__bf16)v.w;
        *(bf16x4*)(hl + row * D + ((c ^ (row & 7)) << 3) + off4) = o;
    }
    __syncthreads();

    const f32x4 vzero = {0.f, 0.f, 0.f, 0.f};
    for (int rl = rlb + w; rl < rlb + RELS_PER_BLOCK; rl += 4) {
        const int r = r0 + rl;
        // load packed W fragments: 8 coalesced 16B loads
        bf16x8 wf[2][4];
        #pragma unroll
        for (int kt = 0; kt < 2; ++kt)
            #pragma unroll
            for (int ot = 0; ot < 4; ++ot)
                wf[kt][ot] = *(const bf16x8*)(Wfrag + ((((size_t)r * 2 + kt) * 4 + ot) * 64 + lane) * 8);

        __bf16* tplane = T + (size_t)rl * N_NODES * D;
        #pragma unroll
        for (int nt = 0; nt < 4; ++nt) {
            const int ln = nt * 16 + m;
            bf16x8 a0 = *(const bf16x8*)(hl + ln * D + (((0 * 4 + q) ^ (ln & 7)) << 3));
            bf16x8 a1 = *(const bf16x8*)(hl + ln * D + (((1 * 4 + q) ^ (ln & 7)) << 3));
            f32x4 acc[4];
            #pragma unroll
            for (int ot = 0; ot < 4; ++ot) acc[ot] = vzero;
            #pragma unroll
            for (int ot = 0; ot < 4; ++ot) {
                acc[ot] = __builtin_amdgcn_mfma_f32_16x16x32_bf16(wf[0][ot], a0, acc[ot], 0, 0, 0);
                acc[ot] = __builtin_amdgcn_mfma_f32_16x16x32_bf16(wf[1][ot], a1, acc[ot], 0, 0, 0);
            }
            const int node = chunk0 + ln;
            if (node < N_NODES) {
                __bf16* trow = tplane + (size_t)node * D;
                #pragma unroll
                for (int ot = 0; ot < 4; ++ot) {
                    bf16x4 o;
                    o[0] = (__bf16)acc[ot][0];
                    o[1] = (__bf16)acc[ot][1];
                    o[2] = (__bf16)acc[ot][2];
                    o[3] = (__bf16)acc[ot][3];
                    *(bf16x4*)(trow + ot * 16 + q * 4) = o;
                }
            }
        }
    }
}

// One wave per dst node; lane = out dim. Per edge: scalar-uniform 8B payload
// load + one coalesced 128B line gather from T (L3-hot) + FMA. Masked 8-wide
// loop (no serial remainder). Plain store; RMW accumulate for g=1.
__global__ __launch_bounds__(256) void k_out(
        const unsigned short* __restrict__ T, const int* __restrict__ offs,
        const int2* __restrict__ pay, float* __restrict__ out,
        int R0, int first) {
    const int v = (blockIdx.x << 2) + (threadIdx.x >> 6);
    const int lane = threadIdx.x & 63;
    int s = __builtin_amdgcn_readfirstlane(offs[v]);
    int e = __builtin_amdgcn_readfirstlane(offs[v + 1]);
    const size_t orow = ((size_t)v << 6) + lane;

    float acc0 = first ? 0.f : out[orow];
    float acc1 = 0.f, acc2 = 0.f, acc3 = 0.f;
    for (int i = s; i < e; i += 8) {
        int2 p[8];
        #pragma unroll
        for (int u = 0; u < 8; ++u) {
            int idx = (i + u < e) ? i + u : e - 1;
            p[u] = pay[idx];
        }
        float tv[8];
        #pragma unroll
        for (int u = 0; u < 8; ++u) {
            int row = (p[u].x & 0x1FFFFF) - R0;
            tv[u] = __uint_as_float(((unsigned int)T[((size_t)row << 6) + lane]) << 16);
        }
        #pragma unroll
        for (int u = 0; u < 8; ++u) {
            float nv = (i + u < e) ? __int_as_float(p[u].y) : 0.f;
            if (u == 0 || u == 4) acc0 = fmaf(nv, tv[u], acc0);
            if (u == 1 || u == 5) acc1 = fmaf(nv, tv[u], acc1);
            if (u == 2 || u == 6) acc2 = fmaf(nv, tv[u], acc2);
            if (u == 3 || u == 7) acc3 = fmaf(nv, tv[u], acc3);
        }
    }
    out[orow] = (acc0 + acc1) + (acc2 + acc3);
}

extern "C" void kernel_launch(void* const* d_in, const int* in_sizes, int n_in,
                              void* d_out, int out_size, void* d_ws, size_t ws_size,
                              hipStream_t stream) {
    const float* h    = (const float*)d_in[0];
    const float* W    = (const float*)d_in[1];
    const int*   src  = (const int*)d_in[2];
    const int*   dst  = (const int*)d_in[3];
    const int*   rel  = (const int*)d_in[4];
    const float* norm = (const float*)d_in[5];
    float* out = (float*)d_out;

    char* ws = (char*)d_ws;
    int*    gcnt  = (int*)(ws);
    int*    base  = (int*)(ws + 0x1000);
    int*    cur   = (int*)(ws + 0x2000);
    int*    offs  = (int*)(ws + 0x3000);
    int2*   pay   = (int2*)(ws + 0x100000);
    __bf16* Wfrag = (__bf16*)(ws + 0xD40000);
    __bf16* T     = (__bf16*)(ws + 0xE00000);   // 102.4 MB, reused per group

    k_zeroc<<<1, 512, 0, stream>>>(gcnt);
    k_hist2<<<SC_BLOCKS, 256, 0, stream>>>(dst, rel, gcnt);
    k_scanc<<<1, 256, 0, stream>>>(gcnt, base, cur);
    k_scatter2<<<SC_BLOCKS, 256, 0, stream>>>(src, dst, rel, norm, cur, pay);
    k_sort<<<NB2, 512, 0, stream>>>(base, pay, offs);
    k_wconv<<<N_REL, 256, 0, stream>>>(W, Wfrag);

    for (int g = 0; g < NGRP; ++g) {
        dim3 pgrid(PRE_BLOCKS, RPG / RELS_PER_BLOCK);
        k_pre<<<pgrid, 256, 0, stream>>>(h, Wfrag, T, g * RPG);
        k_out<<<N_NODES / 4, 256, 0, stream>>>((const unsigned short*)T,
                                               offs + g * (N_NODES + 1), pay, out,
                                               g * RPG * N_NODES, g == 0);
    }
}

// Round 11
// 257.032 us; speedup vs baseline: 1.0564x; 1.0564x over previous
//
#include <hip/hip_runtime.h>

// R-GCN layer: out[v] = sum_{e: dst[e]=v} norm[e] * (h[src[e]] @ W[rel[e]])
//
// v11: v9 base (best measured: 265.8us; G=1, T[rl][n][64] full 204.8MB,
// k_pre at write roofline 68.8us) with ONE change: lean k_scatter2/k_hist2.
// v10's profile exposed scatter2 = 43us latency-bound at 1-3 blocks/CU.
// EPB 8192->4096 (stage 32KB + ushort bid 8KB + 3x391 ints ~ 45KB -> 3
// blocks/CU, 391 blocks vs 196) for ~6x the concurrent waves hiding the
// LDS-atomic ranking chains. G=2 L3-grouping REVERTED (net -5.7us in v10).
//   k_hist2    coarse histogram (391 buckets of 128 nodes)
//   k_scanc    scan of 391 bucket counts
//   k_scatter2 per-block LDS counting sort of 4096 edges -> burst writes
//   k_sort     per-bucket exact sort by dst + offs[]
//   k_wconv    pack W -> per-lane bf16 MFMA fragments
//   k_pre      T[rl][n][:] = bf16(h[n] @ W[r]), h staged once per chunk
//   k_out      one wave per dst node, masked 8-wide gather-FMA, plain store

#define N_NODES 50000
#define N_EDGES 1600000
#define D 64
#define N_REL 32

#define BSHIFT 7                 // 128 nodes per coarse bucket
#define NPB 128
#define NB 391                   // ceil(50000/128)
#define EPB 4096                 // edges per scatter/hist block
#define SC_BLOCKS 391            // ceil(1.6M/4096)
#define SORT_CAP 8192            // bucket capacity (mean 4096, sd 64)

#define PRE_CHUNK 64
#define PRE_BLOCKS 782           // ceil(50000/64)
#define RELS_PER_BLOCK 8

typedef __attribute__((ext_vector_type(8))) __bf16 bf16x8;
typedef __attribute__((ext_vector_type(4))) __bf16 bf16x4;
typedef __attribute__((ext_vector_type(4))) float f32x4;

// ws layout (bytes):
//   [0x0000, 0x1000)      gcnt[NB] ints
//   [0x1000, 0x2000)      base[NB+1] ints
//   [0x2000, 0x3000)      cursor[NB] ints
//   [0x3000, 0x35000)     offs[50001] ints
//   [0x100000, 0xD40000)  payload int2[1.6M] (12.8 MB)
//   [0xD40000, 0xD80000)  Wfrag bf16 [32][2][4][64][8]  (256 KB)
//   [0xE00000, ...)       T bf16 [rpg][N_NODES][64]  (204.8 MB / G)

__global__ __launch_bounds__(512) void k_zeroc(int* __restrict__ gcnt) {
    if (threadIdx.x < NB) gcnt[threadIdx.x] = 0;
}

__global__ __launch_bounds__(256) void k_hist2(const int* __restrict__ dst,
                                               int* __restrict__ gcnt) {
    __shared__ int lc[NB];
    for (int b = threadIdx.x; b < NB; b += 256) lc[b] = 0;
    __syncthreads();
    const int e0 = blockIdx.x * EPB;
    #pragma unroll
    for (int j = 0; j < 16; ++j) {
        int e = e0 + j * 256 + threadIdx.x;
        if (e < N_EDGES) atomicAdd(&lc[dst[e] >> BSHIFT], 1);
    }
    __syncthreads();
    for (int b = threadIdx.x; b < NB; b += 256)
        if (lc[b]) atomicAdd(&gcnt[b], lc[b]);
}

// Exclusive scan of gcnt[0..NB) -> base[0..NB], base[NB]=total; cursor=base.
__global__ __launch_bounds__(512) void k_scanc(const int* __restrict__ gcnt,
                                               int* __restrict__ base,
                                               int* __restrict__ cur) {
    const int t = threadIdx.x;
    const int lane = t & 63;
    const int w = t >> 6;
    int v = (t < NB) ? gcnt[t] : 0;
    int x = v;
    #pragma unroll
    for (int d = 1; d < 64; d <<= 1) {
        int n = __shfl_up(x, d, 64);
        if (lane >= d) x += n;
    }
    __shared__ int wt[8];
    if (lane == 63) wt[w] = x;
    __syncthreads();
    if (t == 0) {
        int run = 0;
        #pragma unroll
        for (int i = 0; i < 8; ++i) { int tmp = wt[i]; wt[i] = run; run += tmp; }
    }
    __syncthreads();
    int excl = x - v + wt[w];
    if (t < NB) { base[t] = excl; cur[t] = excl; }
    if (t == NB - 1) base[NB] = excl + v;
}

// Per-block LDS counting sort of 4096 edges into NB coarse buckets, then
// burst-write contiguous per-bucket runs to globally reserved ranges.
// payload: x = (dstLocal<<21) | (rel*N_NODES + src), y = bits(norm)
__global__ __launch_bounds__(256) void k_scatter2(
        const int* __restrict__ src, const int* __restrict__ dst,
        const int* __restrict__ rel, const float* __restrict__ norm,
        int* __restrict__ cur, int2* __restrict__ pay) {
    __shared__ int cnt[NB];
    __shared__ int bl[NB + 1];
    __shared__ int gb[NB];
    __shared__ unsigned short bid[EPB];
    __shared__ int2 stage[EPB];
    __shared__ int wt[8];

    const int t = threadIdx.x;
    const int lane = t & 63;
    const int w = t >> 6;
    const int e0 = blockIdx.x * EPB;

    for (int b = t; b < NB; b += 256) cnt[b] = 0;
    __syncthreads();

    // pass 1: count
    #pragma unroll
    for (int j = 0; j < 16; ++j) {
        int e = e0 + j * 256 + t;
        if (e < N_EDGES) atomicAdd(&cnt[dst[e] >> BSHIFT], 1);
    }
    __syncthreads();

    // exclusive scan of cnt[0..NB)
    {
        int x0 = (t < NB) ? cnt[t] : 0;
        int x1 = (t + 256 < NB) ? cnt[t + 256] : 0;
        int s0 = x0, s1 = x1;
        #pragma unroll
        for (int d = 1; d < 64; d <<= 1) {
            int n0 = __shfl_up(s0, d, 64);
            int n1 = __shfl_up(s1, d, 64);
            if (lane >= d) { s0 += n0; s1 += n1; }
        }
        if (lane == 63) { wt[w] = s0; wt[4 + w] = s1; }
        __syncthreads();
        if (t == 0) {
            int run = 0;
            #pragma unroll
            for (int i = 0; i < 8; ++i) { int tmp = wt[i]; wt[i] = run; run += tmp; }
        }
        __syncthreads();
        int ex0 = s0 - x0 + wt[w];
        int ex1 = s1 - x1 + wt[4 + w];
        if (t < NB) bl[t] = ex0;
        if (t + 256 < NB) bl[t + 256] = ex1;
        if (t == 0) {
            int tot = (e0 + EPB <= N_EDGES) ? EPB : (N_EDGES > e0 ? N_EDGES - e0 : 0);
            bl[NB] = tot;
        }
    }
    __syncthreads();

    // reserve global ranges (one atomic per non-empty bucket per block)
    for (int b = t; b < NB; b += 256) {
        int c = bl[b + 1] - bl[b];
        gb[b] = c ? atomicAdd(&cur[b], c) : 0;
    }
    for (int b = t; b < NB; b += 256) cnt[b] = 0;
    __syncthreads();

    // pass 2: stage into LDS in bucket-grouped order
    #pragma unroll
    for (int j = 0; j < 16; ++j) {
        int e = e0 + j * 256 + t;
        if (e < N_EDGES) {
            int dv = dst[e];
            int b = dv >> BSHIFT;
            int r = atomicAdd(&cnt[b], 1);
            int pos = bl[b] + r;
            stage[pos] = make_int2(((dv & (NPB - 1)) << 21) | (rel[e] * N_NODES + src[e]),
                                   __float_as_int(norm[e]));
            bid[pos] = (unsigned short)b;
        }
    }
    __syncthreads();

    // pass 3: burst write to global reserved ranges (coalesced runs)
    const int total = bl[NB];
    for (int p = t; p < total; p += 256) {
        int b = bid[p];
        pay[gb[b] + (p - bl[b])] = stage[p];
    }
}

// One block per coarse bucket: stage the bucket's edges in LDS, counting-sort
// by exact local dst, write back IN PLACE in sorted order, and emit per-node
// global offsets (bucket base + local exclusive scan).
__global__ __launch_bounds__(512) void k_sort(
        const int* __restrict__ base, int2* __restrict__ pay,
        int* __restrict__ offs) {
    __shared__ int2 stage[SORT_CAP];   // 64 KB
    __shared__ int cnt[NPB];
    __shared__ int curl[NPB];
    __shared__ int wsum[2];

    const int t = threadIdx.x;
    const int lane = t & 63;
    const int b = blockIdx.x;
    const int s = base[b];
    const int e = base[b + 1];
    const int n = min(e - s, SORT_CAP);   // clamp: overflow degrades, never faults

    if (t < NPB) cnt[t] = 0;
    __syncthreads();

    // stage + count
    for (int j = t; j < n; j += 512) {
        int2 p = pay[s + j];
        stage[j] = p;
        atomicAdd(&cnt[p.x >> 21], 1);
    }
    __syncthreads();

    // exclusive scan of cnt[0..128) with 2 waves
    int vcnt = 0, x = 0;
    if (t < NPB) {
        vcnt = cnt[t];
        x = vcnt;
        #pragma unroll
        for (int d = 1; d < 64; d <<= 1) {
            int nn = __shfl_up(x, d, 64);
            if (lane >= d) x += nn;
        }
        if (lane == 63) wsum[t >> 6] = x;
    }
    __syncthreads();
    if (t < NPB) {
        int excl = x - vcnt + ((t >= 64) ? wsum[0] : 0);
        curl[t] = excl;
        int node = b * NPB + t;
        if (node < N_NODES) offs[node] = s + excl;
    }
    if (b == NB - 1 && t == 0) offs[N_NODES] = e;
    __syncthreads();

    // scatter back in place, sorted by local dst
    for (int j = t; j < n; j += 512) {
        int2 p = stage[j];
        int pos = atomicAdd(&curl[p.x >> 21], 1);
        pay[s + pos] = p;
    }
}

// Pack W into per-lane MFMA A-fragment order:
// Wfrag[r][kt][ot][lane][j] = bf16( W[r][kt*32 + (lane>>4)*8 + j][ot*16 + (lane&15)] )
__global__ __launch_bounds__(256) void k_wconv(const float* __restrict__ W,
                                               __bf16* __restrict__ Wfrag) {
    const int r = blockIdx.x;
    const int lane = threadIdx.x & 63;
    const int jj = (threadIdx.x >> 6) * 2;   // 2 elems per thread per frag
    const int q = lane >> 4;
    const int m = lane & 15;
    const float* Wr = W + (size_t)r * D * D;
    #pragma unroll
    for (int kt = 0; kt < 2; ++kt) {
        #pragma unroll
        for (int ot = 0; ot < 4; ++ot) {
            size_t dbase = ((((size_t)r * 2 + kt) * 4 + ot) * 64 + lane) * 8 + jj;
            Wfrag[dbase]     = (__bf16)Wr[(kt * 32 + q * 8 + jj) * D + ot * 16 + m];
            Wfrag[dbase + 1] = (__bf16)Wr[(kt * 32 + q * 8 + jj + 1) * D + ot * 16 + m];
        }
    }
}

// T[rl][n][:] = h[n] @ W[r0+rl], bf16.  One block per (64-node chunk, 8-rel
// group); h staged once in LDS (bf16, XOR-swizzled 16B chunks); waves loop
// over the block's rels, reading W from packed Wfrag. T is rel-major so each
// fragment store's 16 node-rows fall in one contiguous 2KB window. PLAIN
// stores (L2 write-combining merges the 8B/lane stores into full lines).
__global__ __launch_bounds__(256) void k_pre(
        const float* __restrict__ h, const __bf16* __restrict__ Wfrag,
        __bf16* __restrict__ T, int r0, int rpg) {
    __shared__ unsigned short hl[PRE_CHUNK * D];   // 8 KB
    const int t = threadIdx.x;
    const int lane = t & 63;
    const int w = t >> 6;
    const int m = lane & 15;
    const int q = lane >> 4;
    const int chunk0 = blockIdx.x * PRE_CHUNK;
    const int rlb = blockIdx.y * RELS_PER_BLOCK;
    const int rle = min(rlb + RELS_PER_BLOCK, rpg);

    // stage h[chunk0 .. chunk0+64) as bf16, swizzled
    #pragma unroll
    for (int it = 0; it < 4; ++it) {
        int F = it * 256 + t;                  // float4 index over 64x64 floats
        int row = F >> 4;
        int gnode = min(chunk0 + row, N_NODES - 1);
        float4 v = ((const float4*)(h + (size_t)gnode * D))[F & 15];
        int c = (F & 15) >> 1;
        int off4 = (F & 1) * 4;
        bf16x4 o;
        o[0] = (__bf16)v.x; o[1] = (__bf16)v.y; o[2] = (__bf16)v.z; o[3] = (__bf16)v.w;
        *(bf16x4*)(hl + row * D + ((c ^ (row & 7)) << 3) + off4) = o;
    }
    __syncthreads();

    const f32x4 vzero = {0.f, 0.f, 0.f, 0.f};
    for (int rl = rlb + w; rl < rle; rl += 4) {
        const int r = r0 + rl;
        // load packed W fragments: 8 coalesced 16B loads
        bf16x8 wf[2][4];
        #pragma unroll
        for (int kt = 0; kt < 2; ++kt)
            #pragma unroll
            for (int ot = 0; ot < 4; ++ot)
                wf[kt][ot] = *(const bf16x8*)(Wfrag + ((((size_t)r * 2 + kt) * 4 + ot) * 64 + lane) * 8);

        __bf16* tplane = T + (size_t)rl * N_NODES * D;
        #pragma unroll
        for (int nt = 0; nt < 4; ++nt) {
            const int ln = nt * 16 + m;
            bf16x8 a0 = *(const bf16x8*)(hl + ln * D + (((0 * 4 + q) ^ (ln & 7)) << 3));
            bf16x8 a1 = *(const bf16x8*)(hl + ln * D + (((1 * 4 + q) ^ (ln & 7)) << 3));
            f32x4 acc[4];
            #pragma unroll
            for (int ot = 0; ot < 4; ++ot) acc[ot] = vzero;
            #pragma unroll
            for (int ot = 0; ot < 4; ++ot) {
                acc[ot] = __builtin_amdgcn_mfma_f32_16x16x32_bf16(wf[0][ot], a0, acc[ot], 0, 0, 0);
                acc[ot] = __builtin_amdgcn_mfma_f32_16x16x32_bf16(wf[1][ot], a1, acc[ot], 0, 0, 0);
            }
            const int node = chunk0 + ln;
            if (node < N_NODES) {
                __bf16* trow = tplane + (size_t)node * D;
                #pragma unroll
                for (int ot = 0; ot < 4; ++ot) {
                    bf16x4 o;
                    o[0] = (__bf16)acc[ot][0];
                    o[1] = (__bf16)acc[ot][1];
                    o[2] = (__bf16)acc[ot][2];
                    o[3] = (__bf16)acc[ot][3];
                    *(bf16x4*)(trow + ot * 16 + q * 4) = o;
                }
            }
        }
    }
}

// One wave per dst node; lane = out dim. Per edge: scalar-uniform 8B payload
// load + one coalesced 128B line gather from T + FMA. Plain store, no atomics.
// Masked 8-wide loop: no serial remainder tail (clamp index, zero norm).
__global__ __launch_bounds__(256) void k_out(
        const unsigned short* __restrict__ T, const int* __restrict__ offs,
        const int2* __restrict__ pay, float* __restrict__ out,
        int r0, int r1, int rpg, int first) {
    const int v = (blockIdx.x << 2) + (threadIdx.x >> 6);
    const int lane = threadIdx.x & 63;
    int s = __builtin_amdgcn_readfirstlane(offs[v]);
    int e = __builtin_amdgcn_readfirstlane(offs[v + 1]);
    const size_t orow = ((size_t)v << 6) + lane;

    float acc0 = first ? 0.f : out[orow];
    float acc1 = 0.f, acc2 = 0.f, acc3 = 0.f;
    if (rpg == N_REL) {
        for (int i = s; i < e; i += 8) {
            int2 p[8];
            #pragma unroll
            for (int u = 0; u < 8; ++u) {
                int idx = (i + u < e) ? i + u : e - 1;
                p[u] = pay[idx];
            }
            float tv[8];
            #pragma unroll
            for (int u = 0; u < 8; ++u)
                tv[u] = __uint_as_float(((unsigned int)T[((size_t)(p[u].x & 0x1FFFFF) << 6) + lane]) << 16);
            #pragma unroll
            for (int u = 0; u < 8; ++u) {
                float nv = (i + u < e) ? __int_as_float(p[u].y) : 0.f;
                if (u == 0 || u == 4) acc0 = fmaf(nv, tv[u], acc0);
                if (u == 1 || u == 5) acc1 = fmaf(nv, tv[u], acc1);
                if (u == 2 || u == 6) acc2 = fmaf(nv, tv[u], acc2);
                if (u == 3 || u == 7) acc3 = fmaf(nv, tv[u], acc3);
            }
        }
    } else {
        // grouped fallback (small workspace): only rels in [r0, r1)
        for (int i = s; i < e; ++i) {
            int2 p = pay[i];
            int key = p.x & 0x1FFFFF;
            int rlv = key / N_NODES;
            if (rlv >= r0 && rlv < r1) {
                size_t row = (size_t)(rlv - r0) * N_NODES + (key - rlv * N_NODES);
                float tv = __uint_as_float(((unsigned int)T[(row << 6) + lane]) << 16);
                acc0 = fmaf(__int_as_float(p.y), tv, acc0);
            }
        }
    }
    out[orow] = (acc0 + acc1) + (acc2 + acc3);
}

extern "C" void kernel_launch(void* const* d_in, const int* in_sizes, int n_in,
                              void* d_out, int out_size, void* d_ws, size_t ws_size,
                              hipStream_t stream) {
    const float* h    = (const float*)d_in[0];
    const float* W    = (const float*)d_in[1];
    const int*   src  = (const int*)d_in[2];
    const int*   dst  = (const int*)d_in[3];
    const int*   rel  = (const int*)d_in[4];
    const float* norm = (const float*)d_in[5];
    float* out = (float*)d_out;

    char* ws = (char*)d_ws;
    int*    gcnt  = (int*)(ws);
    int*    base  = (int*)(ws + 0x1000);
    int*    cur   = (int*)(ws + 0x2000);
    int*    offs  = (int*)(ws + 0x3000);
    int2*   pay   = (int2*)(ws + 0x100000);
    __bf16* Wfrag = (__bf16*)(ws + 0xD40000);
    __bf16* T     = (__bf16*)(ws + 0xE00000);

    // Pick the largest rel-group size whose T fits the workspace (expect G=1).
    const size_t tbytes_full = (size_t)N_NODES * N_REL * D * sizeof(__bf16); // 204.8 MB
    int G = 1;
    while (G < N_REL) {
        if ((size_t)0xE00000 + tbytes_full / G <= ws_size) break;
        G <<= 1;
    }
    const int rpg = N_REL / G;

    k_zeroc<<<1, 512, 0, stream>>>(gcnt);
    k_hist2<<<SC_BLOCKS, 256, 0, stream>>>(dst, gcnt);
    k_scanc<<<1, 512, 0, stream>>>(gcnt, base, cur);
    k_scatter2<<<SC_BLOCKS, 256, 0, stream>>>(src, dst, rel, norm, cur, pay);
    k_sort<<<NB, 512, 0, stream>>>(base, pay, offs);
    k_wconv<<<N_REL, 256, 0, stream>>>(W, Wfrag);

    for (int g = 0; g < G; ++g) {
        dim3 pgrid(PRE_BLOCKS, (rpg + RELS_PER_BLOCK - 1) / RELS_PER_BLOCK);
        k_pre<<<pgrid, 256, 0, stream>>>(h, Wfrag, T, g * rpg, rpg);
        k_out<<<N_NODES / 4, 256, 0, stream>>>((const unsigned short*)T, offs, pay, out,
                                               g * rpg, (g + 1) * rpg, rpg, g == 0);
    }
}